// Round 8
// baseline (62.486 us; speedup 1.0000x reference)
//
#include <hip/hip_runtime.h>
#include <math.h>

// B=4, X=128, T=256, HIDDEN=128, EMB=128, DH=32, LATENT=32, K=1024
// Outputs concat: u (131072), zt (1048576), px (524288)
//
// u[b,t,x] = K0 + sum_k zt[b,t,k] * px[b,x,k] * wc[k>>5]   (wc = wcd/32)
//
// ws layout (floats):
//   [0..511]     gx[b][j] = ex @ px_We + px_be
//   [512..1023]  gt[b][j] = et @ zt_We + zt_be
//   [1024..1055] wc[d] = wcd[d]/32
//   [1056]       K0

// prep: 5 blocks x 1024 thr. Slice-reduce each GEMV stage 8-way over k.
__global__ __launch_bounds__(1024) void prep_kernel(
    const float* __restrict__ param,
    const float* __restrict__ p2e_W1, const float* __restrict__ p2e_b1,
    const float* __restrict__ p2e_W2, const float* __restrict__ p2e_b2,
    const float* __restrict__ e2ex_W, const float* __restrict__ e2ex_b,
    const float* __restrict__ e2et_W, const float* __restrict__ e2et_b,
    const float* __restrict__ px_We,  const float* __restrict__ px_be,
    const float* __restrict__ zt_We,  const float* __restrict__ zt_be,
    const float* __restrict__ h0,
    const float* __restrict__ blk_W1, const float* __restrict__ blk_b1,
    const float* __restrict__ blk_Wc, const float* __restrict__ blk_bc,
    const float* __restrict__ blk_W2, const float* __restrict__ blk_b2,
    const float* __restrict__ d_W,    const float* __restrict__ d_b,
    float* __restrict__ ws)
{
    const int tid = threadIdx.x;
    const int j  = tid & 127;
    const int s  = tid >> 7;       // 0..7
    const int kb = s * 16;

    __shared__ float vinA[128], vinB[128];
    __shared__ float part[8][128], partB[8][128];
    __shared__ float wpart[32][8];

    if (blockIdx.x < 4) {
        const int b = blockIdx.x;
        if (s == 0) {
            float a = p2e_b1[j];
            #pragma unroll
            for (int p = 0; p < 16; ++p) a += param[b * 16 + p] * p2e_W1[p * 128 + j];
            vinA[j] = __sinf(a);
        }
        __syncthreads();
        {
            float p = 0.f;
            #pragma unroll
            for (int i = 0; i < 16; ++i) p += vinA[kb + i] * p2e_W2[(kb + i) * 128 + j];
            part[s][j] = p;
        }
        __syncthreads();
        if (s == 0) {
            float e = p2e_b2[j];
            #pragma unroll
            for (int q = 0; q < 8; ++q) e += part[q][j];
            vinB[j] = e;
        }
        __syncthreads();
        {
            float pa = 0.f, pt = 0.f;
            #pragma unroll
            for (int i = 0; i < 16; ++i) {
                const float ek = vinB[kb + i];
                pa += ek * e2ex_W[(kb + i) * 128 + j];
                pt += ek * e2et_W[(kb + i) * 128 + j];
            }
            part[s][j] = pa; partB[s][j] = pt;
        }
        __syncthreads();
        if (s == 0) {
            float ax = e2ex_b[j], at = e2et_b[j];
            #pragma unroll
            for (int q = 0; q < 8; ++q) { ax += part[q][j]; at += partB[q][j]; }
            vinA[j] = ax; vinB[j] = at;
        }
        __syncthreads();
        {
            float pa = 0.f, pt = 0.f;
            #pragma unroll
            for (int i = 0; i < 16; ++i) {
                pa += vinA[kb + i] * px_We[(kb + i) * 128 + j];
                pt += vinB[kb + i] * zt_We[(kb + i) * 128 + j];
            }
            part[s][j] = pa; partB[s][j] = pt;
        }
        __syncthreads();
        if (s == 0) {
            float gx = px_be[j], gt = zt_be[j];
            #pragma unroll
            for (int q = 0; q < 8; ++q) { gx += part[q][j]; gt += partB[q][j]; }
            ws[b * 128 + j]       = gx;
            ws[512 + b * 128 + j] = gt;
        }
    } else {
        {
            float p = 0.f;
            #pragma unroll
            for (int i = 0; i < 16; ++i) p += h0[kb + i] * blk_W1[(kb + i) * 128 + j];
            part[s][j] = p;
        }
        {
            float p = 0.f;
            #pragma unroll
            for (int i = 0; i < 16; ++i) p += blk_W2[j * 128 + kb + i] * d_W[kb + i];
            partB[s][j] = p;
        }
        __syncthreads();
        if (s == 0) {
            float sa = blk_b1[j], w2 = 0.f;
            #pragma unroll
            for (int q = 0; q < 8; ++q) { sa += part[q][j]; w2 += partB[q][j]; }
            const float sw = __sinf(sa) * w2;
            vinA[j] = sw;
            vinB[j] = (h0[j] + blk_b2[j]) * d_W[j] + sw * blk_bc[j];
        }
        __syncthreads();
        if (tid < 256) {
            const int d  = tid >> 3;
            const int s3 = (tid & 7) * 16;
            float p = 0.f;
            #pragma unroll
            for (int i = 0; i < 16; ++i) p += blk_Wc[d * 128 + s3 + i] * vinA[s3 + i];
            wpart[d][tid & 7] = p;
        }
        __syncthreads();
        if (tid < 32) {
            float w = 0.f;
            #pragma unroll
            for (int q = 0; q < 8; ++q) w += wpart[tid][q];
            ws[1024 + tid] = w * (1.0f / 32.0f);
        }
        if (tid < 64) part[0][tid] = vinB[tid] + vinB[tid + 64];
        __syncthreads();
        if (tid < 32) part[0][tid] += part[0][tid + 32];
        if (tid < 16) part[0][tid] += part[0][tid + 16];
        if (tid < 8)  part[0][tid] += part[0][tid + 8];
        if (tid < 4)  part[0][tid] += part[0][tid + 4];
        if (tid < 2)  part[0][tid] += part[0][tid + 2];
        if (tid == 0) ws[1056] = part[0][0] + part[0][1] + d_b[0];
    }
}

__device__ __forceinline__ void fma4(float4& a, float s, const float4& v) {
    a.x += s * v.x; a.y += s * v.y; a.z += s * v.z; a.w += s * v.w;
}

__device__ __forceinline__ void loadw(float4 (&w)[8], const float* __restrict__ wp,
                                      int g) {
    #pragma unroll
    for (int i = 0; i < 8; ++i)
        w[i] = *(const float4*)&wp[(g * 8 + i) * 1024];
}

__device__ __forceinline__ void consume8(float4 (&acc)[8], const float4 (&w)[8],
                                         const float (*f)[128], int k0) {
    #pragma unroll
    for (int rr = 0; rr < 8; ++rr) {
        const float4 f0 = *(const float4*)&f[rr][k0];
        const float4 f1 = *(const float4*)&f[rr][k0 + 4];
        fma4(acc[rr], f0.x, w[0]); fma4(acc[rr], f0.y, w[1]);
        fma4(acc[rr], f0.z, w[2]); fma4(acc[rr], f0.w, w[3]);
        fma4(acc[rr], f1.x, w[4]); fma4(acc[rr], f1.y, w[5]);
        fma4(acc[rr], f1.z, w[6]); fma4(acc[rr], f1.w, w[7]);
    }
}

// feat: 384 blocks x 128 thr. blk<128: px (rt=blk>>1, cs=blk&1), else zt.
// Block: 8 rows x 512 cols. Triple-buffered weight pipeline: 24 float4 loads
// in flight; 2 consume-groups (256 cy) cover each group's L2 latency.
__global__ __launch_bounds__(128, 1) void feat_kernel(
    const float* __restrict__ x, const float* __restrict__ t,
    const float* __restrict__ px_Wx, const float* __restrict__ px_bx,
    const float* __restrict__ px_Wo, const float* __restrict__ px_bo,
    const float* __restrict__ px_mult,
    const float* __restrict__ zt_Wx, const float* __restrict__ zt_bx,
    const float* __restrict__ zt_Wo, const float* __restrict__ zt_bo,
    const float* __restrict__ zt_mult,
    const float* __restrict__ ws,
    float* __restrict__ out_px, float* __restrict__ out_zt)
{
    const int tid = threadIdx.x;
    const bool is_zt = (blockIdx.x >= 128);
    const int idx = is_zt ? ((int)blockIdx.x - 128) : (int)blockIdx.x;
    const int rt = idx >> 1;
    const int cs = idx & 1;
    const int r0 = rt * 8;
    const int b  = is_zt ? (r0 >> 8) : (r0 >> 7);

    const float* Wx = is_zt ? zt_Wx : px_Wx;
    const float* bx = is_zt ? zt_bx : px_bx;
    const float* Wo = is_zt ? zt_Wo : px_Wo;
    const float* bo = is_zt ? zt_bo : px_bo;
    const float* coord = is_zt ? t : x;
    const float  mult  = is_zt ? zt_mult[0] : px_mult[0];
    const float* g = ws + (is_zt ? 512 : 0) + b * 128;
    float* outp = is_zt ? out_zt : out_px;

    __shared__ float f[8][128];
    {
        const float gv = g[tid];
        const float wxj = Wx[tid], bxj = bx[tid];
        #pragma unroll
        for (int rr = 0; rr < 8; ++rr)
            f[rr][tid] = __sinf(coord[r0 + rr] * wxj + bxj) * gv;
    }
    __syncthreads();

    const int c0 = cs * 512 + tid * 4;
    const float* wp = Wo + c0;

    const float4 bias = *(const float4*)&bo[c0];
    float4 acc[8];
    #pragma unroll
    for (int rr = 0; rr < 8; ++rr) acc[rr] = bias;

    float4 wA[8], wB[8], wC[8];
    loadw(wA, wp, 0); loadw(wB, wp, 1); loadw(wC, wp, 2);

    consume8(acc, wA, f, 0);    loadw(wA, wp, 3);
    consume8(acc, wB, f, 8);    loadw(wB, wp, 4);
    consume8(acc, wC, f, 16);   loadw(wC, wp, 5);
    consume8(acc, wA, f, 24);   loadw(wA, wp, 6);
    consume8(acc, wB, f, 32);   loadw(wB, wp, 7);
    consume8(acc, wC, f, 40);   loadw(wC, wp, 8);
    consume8(acc, wA, f, 48);   loadw(wA, wp, 9);
    consume8(acc, wB, f, 56);   loadw(wB, wp, 10);
    consume8(acc, wC, f, 64);   loadw(wC, wp, 11);
    consume8(acc, wA, f, 72);   loadw(wA, wp, 12);
    consume8(acc, wB, f, 80);   loadw(wB, wp, 13);
    consume8(acc, wC, f, 88);   loadw(wC, wp, 14);
    consume8(acc, wA, f, 96);   loadw(wA, wp, 15);
    consume8(acc, wB, f, 104);
    consume8(acc, wC, f, 112);
    consume8(acc, wA, f, 120);

    #pragma unroll
    for (int rr = 0; rr < 8; ++rr) {
        float4 v;
        v.x = mult * acc[rr].x; v.y = mult * acc[rr].y;
        v.z = mult * acc[rr].z; v.w = mult * acc[rr].w;
        *(float4*)&outp[(r0 + rr) * 1024 + c0] = v;
    }
}

// u: 512 blocks = 4b x 32 t-tiles(8 rows) x 4 x-quarters(32). 128 thr.
// Thread (tx=tid&31, ty=tid>>5 in 0..3): outputs rows t0+ty, t0+ty+4, col x0+tx.
// Full k in 4 chunks of 256; px chunk staged in LDS pre-scaled by wc;
// zt rows register-prefetched 1 jj-group ahead (16 f4 in flight).
__global__ __launch_bounds__(128) void u_kernel(
    const float* __restrict__ zt, const float* __restrict__ px,
    const float* __restrict__ ws, float* __restrict__ out_u)
{
    const int tid = threadIdx.x;
    const int blk = blockIdx.x;
    const int b   = blk >> 7;
    const int rem = blk & 127;
    const int t0  = (rem >> 2) * 8;
    const int x0  = (rem & 3) * 32;

    __shared__ float4 pxs4[32][65];
    __shared__ float wcs[32];
    if (tid < 32) wcs[tid] = ws[1024 + tid];
    const float K0 = ws[1056];

    const int tx = tid & 31;
    const int ty = tid >> 5;          // 0..3

    const float* ztb = zt + (b * 256 + t0) * 1024;
    const float* pxb = px + (b * 128 + x0) * 1024;
    __syncthreads();                  // wcs visible

    float acc0 = 0.f, acc1 = 0.f;

    for (int chunk = 0; chunk < 4; ++chunk) {
        const int kc = chunk * 256;
        if (chunk) __syncthreads();
        // stage px chunk: 32 x-rows x 64 f4, scaled; 16 f4 per thread
        #pragma unroll
        for (int i = 0; i < 16; ++i) {
            const int m  = tid + 128 * i;
            const int xx = m >> 6;
            const int jf = m & 63;
            float4 v = *(const float4*)&pxb[xx * 1024 + kc + jf * 4];
            const float sc = wcs[(kc >> 5) + (jf >> 3)];
            v.x *= sc; v.y *= sc; v.z *= sc; v.w *= sc;
            pxs4[xx][jf] = v;
        }
        __syncthreads();

        float4 za[8], zb[8];
        #pragma unroll
        for (int j2 = 0; j2 < 8; ++j2) {
            za[j2] = *(const float4*)&ztb[ty * 1024 + kc + j2 * 4];
            zb[j2] = *(const float4*)&ztb[(ty + 4) * 1024 + kc + j2 * 4];
        }
        #pragma unroll
        for (int jj = 0; jj < 8; ++jj) {
            float4 nza[8], nzb[8];
            if (jj < 7) {
                const int koff = kc + (jj + 1) * 32;
                #pragma unroll
                for (int j2 = 0; j2 < 8; ++j2) {
                    nza[j2] = *(const float4*)&ztb[ty * 1024 + koff + j2 * 4];
                    nzb[j2] = *(const float4*)&ztb[(ty + 4) * 1024 + koff + j2 * 4];
                }
            }
            #pragma unroll
            for (int j2 = 0; j2 < 8; ++j2) {
                const float4 p = pxs4[tx][jj * 8 + j2];
                acc0 += za[j2].x * p.x + za[j2].y * p.y
                      + za[j2].z * p.z + za[j2].w * p.w;
                acc1 += zb[j2].x * p.x + zb[j2].y * p.y
                      + zb[j2].z * p.z + zb[j2].w * p.w;
            }
            if (jj < 7) {
                #pragma unroll
                for (int j2 = 0; j2 < 8; ++j2) { za[j2] = nza[j2]; zb[j2] = nzb[j2]; }
            }
        }
    }

    out_u[(b * 256 + t0 + ty)     * 128 + x0 + tx] = K0 + acc0;
    out_u[(b * 256 + t0 + ty + 4) * 128 + x0 + tx] = K0 + acc1;
}

extern "C" void kernel_launch(void* const* d_in, const int* in_sizes, int n_in,
                              void* d_out, int out_size, void* d_ws, size_t ws_size,
                              hipStream_t stream) {
    const float* x       = (const float*)d_in[0];
    const float* t       = (const float*)d_in[1];
    const float* param   = (const float*)d_in[2];
    const float* p2e_W1  = (const float*)d_in[3];
    const float* p2e_b1  = (const float*)d_in[4];
    const float* p2e_W2  = (const float*)d_in[5];
    const float* p2e_b2  = (const float*)d_in[6];
    const float* e2ex_W  = (const float*)d_in[7];
    const float* e2ex_b  = (const float*)d_in[8];
    const float* e2et_W  = (const float*)d_in[9];
    const float* e2et_b  = (const float*)d_in[10];
    const float* px_Wx   = (const float*)d_in[11];
    const float* px_bx   = (const float*)d_in[12];
    const float* px_We   = (const float*)d_in[13];
    const float* px_be   = (const float*)d_in[14];
    const float* px_Wo   = (const float*)d_in[15];
    const float* px_bo   = (const float*)d_in[16];
    const float* px_mult = (const float*)d_in[17];
    const float* zt_Wx   = (const float*)d_in[18];
    const float* zt_bx   = (const float*)d_in[19];
    const float* zt_We   = (const float*)d_in[20];
    const float* zt_be   = (const float*)d_in[21];
    const float* zt_Wo   = (const float*)d_in[22];
    const float* zt_bo   = (const float*)d_in[23];
    const float* zt_mult = (const float*)d_in[24];
    const float* h0      = (const float*)d_in[25];
    const float* blk_W1  = (const float*)d_in[26];
    const float* blk_b1  = (const float*)d_in[27];
    const float* blk_Wc  = (const float*)d_in[28];
    const float* blk_bc  = (const float*)d_in[29];
    const float* blk_W2  = (const float*)d_in[30];
    const float* blk_b2  = (const float*)d_in[31];
    const float* d_W     = (const float*)d_in[32];
    const float* d_bias  = (const float*)d_in[33];

    float* out    = (float*)d_out;
    float* out_u  = out;                       // 131072
    float* out_zt = out + 131072;              // 1048576
    float* out_px = out + 131072 + 1048576;    // 524288

    float* ws = (float*)d_ws;

    prep_kernel<<<5, 1024, 0, stream>>>(
        param, p2e_W1, p2e_b1, p2e_W2, p2e_b2,
        e2ex_W, e2ex_b, e2et_W, e2et_b,
        px_We, px_be, zt_We, zt_be,
        h0, blk_W1, blk_b1, blk_Wc, blk_bc, blk_W2, blk_b2,
        d_W, d_bias, ws);

    feat_kernel<<<384, 128, 0, stream>>>(
        x, t,
        px_Wx, px_bx, px_Wo, px_bo, px_mult,
        zt_Wx, zt_bx, zt_Wo, zt_bo, zt_mult,
        ws, out_px, out_zt);

    u_kernel<<<512, 128, 0, stream>>>(out_zt, out_px, ws, out_u);
}